// Round 4
// baseline (571.004 us; speedup 1.0000x reference)
//
#include <hip/hip_runtime.h>
#include <math.h>

// Problem constants (hard-coded per reference)
#define B_  8192
#define T_  204
#define I_  5
#define H_  24
#define L_  10
#define O_  612

#define TPE 48                // threads per element: 2 per hidden unit (p=0: gates i,f; p=1: g,o)
#define EPB 4                 // elements per block
#define BLK (EPB * TPE)       // 192 threads = 3 waves

__device__ __forceinline__ float fast_rcp(float x) {
    return __builtin_amdgcn_rcpf(x);
}
__device__ __forceinline__ float sigm(float x) {
    // 1/(1+e^-x); e^-x overflows to +inf for very negative x -> rcp(inf)=0 (correct)
    return fast_rcp(1.0f + __expf(-x));
}
__device__ __forceinline__ float tanh_fast(float x) {
    float ax = fabsf(x);
    float e  = __expf(-2.0f * ax);
    float r  = (1.0f - e) * fast_rcp(1.0f + e);
    return copysignf(r, x);
}

// R3 post-mortem: allocator's occupancy heuristic targeted ~8 waves/EU
// (VGPR_Count=52) and spilled the ~118 loop-carried weight floats to AGPRs;
// per-use v_accvgpr_read tripled VALU issue (measured 240us VALU vs 80us model).
// amdgpu_waves_per_eu(3,3) pins the allocator's target at 3 waves/EU ->
// 170-VGPR budget -> weights stay in arch VGPRs.
__global__ __launch_bounds__(BLK)
__attribute__((amdgpu_waves_per_eu(3, 3)))
void lstm_fused_kernel(const float* __restrict__ x,
                       const float* __restrict__ W_ih,
                       const float* __restrict__ W_hh,
                       const float* __restrict__ b_ih,
                       const float* __restrict__ b_hh,
                       const float* __restrict__ fc0_w,
                       const float* __restrict__ fc0_b,
                       const float* __restrict__ out_w,
                       const float* __restrict__ out_b,
                       float* __restrict__ out)
{
    __shared__ __align__(16) float h_buf[2][EPB][H_];       // 768 B
    __shared__ __align__(16) float x_buf[2][EPB][8];        // 256 B
    __shared__ __align__(16) float red[EPB][2][H_][L_/2];   // 3840 B fc0 partials
    __shared__ __align__(16) float act[EPB][L_];            // 160 B

    const int tid = threadIdx.x;
    const int e   = tid / TPE;            // element within block
    const int r   = tid - e * TPE;        // 0..47
    const int j   = r >> 1;               // hidden unit 0..23
    const int p   = r & 1;                // gate pair: 0 -> (i,f), 1 -> (g,o)
    const int b   = blockIdx.x * EPB + e;

    // ---- preload this thread's 2 gate rows (torch order i,f,g,o) ----
    const int rowA = (p ? 2 : 0) * H_ + j;   // i or g
    const int rowB = (p ? 3 : 1) * H_ + j;   // f or o
    float whhA[H_], whhB[H_], wihA[I_], wihB[I_];
    {
        const float4* wa = reinterpret_cast<const float4*>(W_hh + rowA * H_);
        const float4* wb = reinterpret_cast<const float4*>(W_hh + rowB * H_);
        #pragma unroll
        for (int k4 = 0; k4 < H_ / 4; ++k4) {
            float4 a = wa[k4], bb = wb[k4];
            whhA[k4*4+0]=a.x; whhA[k4*4+1]=a.y; whhA[k4*4+2]=a.z; whhA[k4*4+3]=a.w;
            whhB[k4*4+0]=bb.x; whhB[k4*4+1]=bb.y; whhB[k4*4+2]=bb.z; whhB[k4*4+3]=bb.w;
        }
        #pragma unroll
        for (int i = 0; i < I_; ++i) { wihA[i] = W_ih[rowA*I_+i]; wihB[i] = W_ih[rowB*I_+i]; }
    }
    const float biasA = b_ih[rowA] + b_hh[rowA];
    const float biasB = b_ih[rowB] + b_hh[rowB];

    // fc0 rows owned by this thread: l = p*5 .. p*5+4, column t*24+j
    const float* fw = fc0_w + (size_t)(p * (L_/2)) * (T_ * H_) + j;
    float facc[L_/2];
    #pragma unroll
    for (int l = 0; l < L_/2; ++l) facc[l] = 0.0f;

    // ---- init state ----
    const float* xp = x + (size_t)b * (T_ * I_);
    if (r < H_) h_buf[0][e][r] = 0.0f;
    if (r < I_) x_buf[0][e][r] = xp[r];
    float c = 0.0f;

    // ---- time loop ----
    for (int t = 0; t < T_; ++t) {
        __syncthreads();   // publishes h_buf/x_buf[t&1] written last iteration
        const int cur = t & 1, nxt = cur ^ 1;

        float aA = biasA, aB = biasB;

        #pragma unroll
        for (int i = 0; i < I_; ++i) {
            const float xv = x_buf[cur][e][i];
            aA = fmaf(wihA[i], xv, aA);
            aB = fmaf(wihB[i], xv, aB);
        }

        const float4* h4p = reinterpret_cast<const float4*>(&h_buf[cur][e][0]);
        #pragma unroll
        for (int k4 = 0; k4 < H_ / 4; ++k4) {
            const float4 hv = h4p[k4];
            #pragma unroll
            for (int u = 0; u < 4; ++u) {
                const float hk = (&hv.x)[u];
                const int k = k4 * 4 + u;
                aA = fmaf(whhA[k], hk, aA);
                aB = fmaf(whhB[k], hk, aB);
            }
        }

        // Uniform activation: p=0 -> gA=sigm(aA) [i], p=1 -> gA=tanh(aA)=2*sigm(2aA)-1 [g]
        // gB = sigm(aB) for both (f and o are sigmoids).
        const float sA = sigm(p ? 2.0f * aA : aA);
        const float gA = p ? 2.0f * sA - 1.0f : sA;     // i_s (p=0) or g_t (p=1)
        const float gB = sigm(aB);                      // f_s (p=0) or o_s (p=1)

        // exchange with partner lane (lane^1): each lane then holds all 4 gates
        const float oA = __shfl_xor(gA, 1, 64);
        const float oB = __shfl_xor(gB, 1, 64);
        const float i_s = p ? oA : gA;
        const float f_s = p ? oB : gB;
        const float g_t = p ? gA : oA;
        const float o_s = p ? gB : oB;

        // both lanes maintain identical c/h (no divergence, no second exchange)
        c = fmaf(f_s, c, i_s * g_t);
        const float h = o_s * tanh_fast(c);

        if (p == 0) h_buf[nxt][e][j] = h;
        if (r < I_ && (t + 1) < T_) x_buf[nxt][e][r] = xp[(t + 1) * I_ + r];

        // fc0 partial accumulation (5 rows per thread)
        const int col = t * H_;
        #pragma unroll
        for (int l = 0; l < L_/2; ++l)
            facc[l] = fmaf(fw[(size_t)l * (T_ * H_) + col], h, facc[l]);
    }

    // ---- fc0 reduction across the 24 units ----
    #pragma unroll
    for (int l = 0; l < L_/2; ++l) red[e][p][j][l] = facc[l];
    __syncthreads();

    if (tid < EPB * L_) {
        const int ee = tid / L_, l = tid - ee * L_;
        const int pp = l / (L_/2), li = l - pp * (L_/2);
        float s = fc0_b[l];
        #pragma unroll
        for (int k = 0; k < H_; ++k) s += red[ee][pp][k][li];
        act[ee][l] = fmaxf(s, 0.0f);
    }
    __syncthreads();

    // ---- output layer: [EPB,10] x [612,10]^T ----
    for (int idx = tid; idx < EPB * O_; idx += BLK) {
        const int ee = idx / O_, o = idx - ee * O_;
        float s = out_b[o];
        #pragma unroll
        for (int l = 0; l < L_; ++l)
            s = fmaf(act[ee][l], out_w[o * L_ + l], s);
        out[(size_t)(blockIdx.x * EPB + ee) * O_ + o] = s;
    }
}

extern "C" void kernel_launch(void* const* d_in, const int* in_sizes, int n_in,
                              void* d_out, int out_size, void* d_ws, size_t ws_size,
                              hipStream_t stream)
{
    const float* x     = (const float*)d_in[0];
    const float* W_ih  = (const float*)d_in[1];
    const float* W_hh  = (const float*)d_in[2];
    const float* b_ih  = (const float*)d_in[3];
    const float* b_hh  = (const float*)d_in[4];
    const float* fc0_w = (const float*)d_in[5];
    const float* fc0_b = (const float*)d_in[6];
    const float* out_w = (const float*)d_in[7];
    const float* out_b = (const float*)d_in[8];
    float* out = (float*)d_out;

    dim3 grid(B_ / EPB);   // 2048 blocks
    dim3 block(BLK);       // 192 threads
    lstm_fused_kernel<<<grid, block, 0, stream>>>(
        x, W_ih, W_hh, b_ih, b_hh, fc0_w, fc0_b, out_w, out_b, out);
}

// Round 5
// 441.573 us; speedup vs baseline: 1.2931x; 1.2931x over previous
//
#include <hip/hip_runtime.h>
#include <math.h>

// Problem constants (hard-coded per reference)
#define B_  8192
#define T_  204
#define I_  5
#define H_  24
#define L_  10
#define O_  612

#define TPE 48                // threads per element: 2 per hidden unit (p=0: gates i,f; p=1: g,o)
#define EPB 4                 // elements per block
#define BLK (EPB * TPE)       // 192 threads = 3 waves

typedef _Float16 h2 __attribute__((ext_vector_type(2)));

#if defined(__has_builtin)
#  if __has_builtin(__builtin_amdgcn_fdot2)
#    define HAVE_FDOT2 1
#  endif
#endif
#ifndef HAVE_FDOT2
#  define HAVE_FDOT2 0
#endif

__device__ __forceinline__ float dot2(h2 a, h2 b, float c) {
#if HAVE_FDOT2
    return __builtin_amdgcn_fdot2(a, b, c, false);   // v_dot2_f32_f16, fp32 accum
#else
    return fmaf((float)a.x, (float)b.x, fmaf((float)a.y, (float)b.y, c));
#endif
}

__device__ __forceinline__ float fast_rcp(float x) {
    return __builtin_amdgcn_rcpf(x);
}
__device__ __forceinline__ float sigm(float x) {
    return fast_rcp(1.0f + __expf(-x));
}
__device__ __forceinline__ float tanh_fast(float x) {
    float ax = fabsf(x);
    float e  = __expf(-2.0f * ax);
    float r  = (1.0f - e) * fast_rcp(1.0f + e);
    return copysignf(r, x);
}

// R4 post-mortem: allocator parks >64 loop-carried floats in AGPRs regardless
// of waves_per_eu; per-use moves ~2.4x the VALU stream. Fix: fp16 dot2 path --
// packed half2 weights (~32 regs) + halved MAC count; total live ~60 VGPRs.
__global__ __launch_bounds__(BLK)
void lstm_fused_kernel(const float* __restrict__ x,
                       const float* __restrict__ W_ih,
                       const float* __restrict__ W_hh,
                       const float* __restrict__ b_ih,
                       const float* __restrict__ b_hh,
                       const float* __restrict__ fc0_w,
                       const float* __restrict__ fc0_b,
                       const float* __restrict__ out_w,
                       const float* __restrict__ out_b,
                       float* __restrict__ out)
{
    __shared__ __align__(16) _Float16 h_sh[2][EPB][H_];     // 48B rows, double-buffered
    __shared__ __align__(16) _Float16 x_sh[2][EPB][8];      // 16B rows (5 used + 3 zero pad)
    __shared__ __align__(16) float red[EPB][2][H_][L_/2];   // fc0 partials
    __shared__ __align__(16) float act[EPB][L_];

    const int tid = threadIdx.x;
    const int e   = tid / TPE;            // element within block
    const int r   = tid - e * TPE;        // 0..47
    const int j   = r >> 1;               // hidden unit 0..23
    const int p   = r & 1;                // gate pair: 0 -> (i,f), 1 -> (g,o)
    const int b   = blockIdx.x * EPB + e;

    // ---- preload this thread's 2 gate rows, packed fp16 (torch order i,f,g,o) ----
    const int rowA = (p ? 2 : 0) * H_ + j;   // i or g
    const int rowB = (p ? 3 : 1) * H_ + j;   // f or o
    h2 whhA2[H_/2], whhB2[H_/2], wihA2[3], wihB2[3];
    {
        const float* wa = W_hh + rowA * H_;
        const float* wb = W_hh + rowB * H_;
        #pragma unroll
        for (int k2 = 0; k2 < H_/2; ++k2) {
            whhA2[k2] = h2{(_Float16)wa[2*k2], (_Float16)wa[2*k2+1]};
            whhB2[k2] = h2{(_Float16)wb[2*k2], (_Float16)wb[2*k2+1]};
        }
        const float* ia = W_ih + rowA * I_;
        const float* ib = W_ih + rowB * I_;
        wihA2[0] = h2{(_Float16)ia[0], (_Float16)ia[1]};
        wihA2[1] = h2{(_Float16)ia[2], (_Float16)ia[3]};
        wihA2[2] = h2{(_Float16)ia[4], (_Float16)0.0f};
        wihB2[0] = h2{(_Float16)ib[0], (_Float16)ib[1]};
        wihB2[1] = h2{(_Float16)ib[2], (_Float16)ib[3]};
        wihB2[2] = h2{(_Float16)ib[4], (_Float16)0.0f};
    }
    const float biasA = b_ih[rowA] + b_hh[rowA];
    const float biasB = b_ih[rowB] + b_hh[rowB];

    // fc0 rows owned by this thread: l = p*5 .. p*5+4, column t*24+j
    const float* fw = fc0_w + (size_t)(p * (L_/2)) * (T_ * H_) + j;
    float facc[L_/2];
    #pragma unroll
    for (int l = 0; l < L_/2; ++l) facc[l] = 0.0f;

    // ---- init state ----
    const float* xp = x + (size_t)b * (T_ * I_);
    if (r < H_) h_sh[0][e][r] = (_Float16)0.0f;
    if (r < 8) { x_sh[0][e][r] = (_Float16)0.0f; x_sh[1][e][r] = (_Float16)0.0f; }
    if (r < I_) x_sh[0][e][r] = (_Float16)xp[r];
    float c = 0.0f;

    union V4 { float4 f; h2 h[4]; };

    // ---- time loop ----
    for (int t = 0; t < T_; ++t) {
        __syncthreads();   // publishes h_sh/x_sh[t&1] written last iteration
        const int cur = t & 1, nxt = cur ^ 1;

        float aA = biasA, aB = biasB;

        // input projection (x broadcast from LDS, fp16 pairs; pads are 0*0)
        {
            V4 xu; xu.f = *reinterpret_cast<const float4*>(&x_sh[cur][e][0]);
            aA = dot2(wihA2[0], xu.h[0], aA);
            aB = dot2(wihB2[0], xu.h[0], aB);
            aA = dot2(wihA2[1], xu.h[1], aA);
            aB = dot2(wihB2[1], xu.h[1], aB);
            aA = dot2(wihA2[2], xu.h[2], aA);
            aB = dot2(wihB2[2], xu.h[2], aB);
        }

        // recurrent projection: 3x ds_read_b128 -> 12 h2 pairs, 24 dot2
        {
            const float4* hp4 = reinterpret_cast<const float4*>(&h_sh[cur][e][0]);
            V4 u0, u1, u2;
            u0.f = hp4[0]; u1.f = hp4[1]; u2.f = hp4[2];
            #pragma unroll
            for (int q = 0; q < 4; ++q) {
                aA = dot2(whhA2[q],     u0.h[q], aA);
                aB = dot2(whhB2[q],     u0.h[q], aB);
                aA = dot2(whhA2[4 + q], u1.h[q], aA);
                aB = dot2(whhB2[4 + q], u1.h[q], aB);
                aA = dot2(whhA2[8 + q], u2.h[q], aA);
                aB = dot2(whhB2[8 + q], u2.h[q], aB);
            }
        }

        // Uniform activation: p=0 -> gA=sigm(aA) [i], p=1 -> gA=tanh(aA)=2*sigm(2aA)-1 [g]
        const float sA = sigm(p ? 2.0f * aA : aA);
        const float gA = p ? 2.0f * sA - 1.0f : sA;     // i_s (p=0) or g_t (p=1)
        const float gB = sigm(aB);                      // f_s (p=0) or o_s (p=1)

        // exchange with partner lane (lane^1): each lane then holds all 4 gates
        const float oA = __shfl_xor(gA, 1, 64);
        const float oB = __shfl_xor(gB, 1, 64);
        const float i_s = p ? oA : gA;
        const float f_s = p ? oB : gB;
        const float g_t = p ? gA : oA;
        const float o_s = p ? gB : oB;

        // both lanes maintain identical c/h (no divergence, no second exchange)
        c = fmaf(f_s, c, i_s * g_t);
        const float h = o_s * tanh_fast(c);

        if (p == 0) h_sh[nxt][e][j] = (_Float16)h;
        if (r < I_ && (t + 1) < T_) x_sh[nxt][e][r] = (_Float16)xp[(t + 1) * I_ + r];

        // fc0 partial accumulation (5 rows per thread, fp32)
        const int col = t * H_;
        #pragma unroll
        for (int l = 0; l < L_/2; ++l)
            facc[l] = fmaf(fw[(size_t)l * (T_ * H_) + col], h, facc[l]);
    }

    // ---- fc0 reduction across the 24 units ----
    #pragma unroll
    for (int l = 0; l < L_/2; ++l) red[e][p][j][l] = facc[l];
    __syncthreads();

    if (tid < EPB * L_) {
        const int ee = tid / L_, l = tid - ee * L_;
        const int pp = l / (L_/2), li = l - pp * (L_/2);
        float s = fc0_b[l];
        #pragma unroll
        for (int k = 0; k < H_; ++k) s += red[ee][pp][k][li];
        act[ee][l] = fmaxf(s, 0.0f);
    }
    __syncthreads();

    // ---- output layer: [EPB,10] x [612,10]^T ----
    for (int idx = tid; idx < EPB * O_; idx += BLK) {
        const int ee = idx / O_, o = idx - ee * O_;
        float s = out_b[o];
        #pragma unroll
        for (int l = 0; l < L_; ++l)
            s = fmaf(act[ee][l], out_w[o * L_ + l], s);
        out[(size_t)(blockIdx.x * EPB + ee) * O_ + o] = s;
    }
}

extern "C" void kernel_launch(void* const* d_in, const int* in_sizes, int n_in,
                              void* d_out, int out_size, void* d_ws, size_t ws_size,
                              hipStream_t stream)
{
    const float* x     = (const float*)d_in[0];
    const float* W_ih  = (const float*)d_in[1];
    const float* W_hh  = (const float*)d_in[2];
    const float* b_ih  = (const float*)d_in[3];
    const float* b_hh  = (const float*)d_in[4];
    const float* fc0_w = (const float*)d_in[5];
    const float* fc0_b = (const float*)d_in[6];
    const float* out_w = (const float*)d_in[7];
    const float* out_b = (const float*)d_in[8];
    float* out = (float*)d_out;

    dim3 grid(B_ / EPB);   // 2048 blocks
    dim3 block(BLK);       // 192 threads
    lstm_fused_kernel<<<grid, block, 0, stream>>>(
        x, W_ih, W_hh, b_ih, b_hh, fc0_w, fc0_b, out_w, out_b, out);
}

// Round 7
// 326.565 us; speedup vs baseline: 1.7485x; 1.3522x over previous
//
#include <hip/hip_runtime.h>
#include <math.h>

// Problem constants
#define T_  204
#define I_  5
#define H_  24
#define L_  10
#define O_  612
#define Bsz 8192
#define G_  96          // 4*H gate rows

typedef _Float16 half8 __attribute__((ext_vector_type(8)));
typedef _Float16 half2t __attribute__((ext_vector_type(2)));
typedef float    float4t __attribute__((ext_vector_type(4)));

union U16B { float4t f4; half8 h8; float f[4]; _Float16 h[8]; half2t h2[4]; };

__device__ __forceinline__ float fast_rcp(float x){ return __builtin_amdgcn_rcpf(x); }
__device__ __forceinline__ float fast_ex2(float x){ return __builtin_amdgcn_exp2f(x); }
__device__ __forceinline__ half2t pk2(float a, float b){
    return __builtin_bit_cast(half2t, __builtin_amdgcn_cvt_pkrtz(a, b));
}

#define MFMA16(a,b,c) __builtin_amdgcn_mfma_f32_16x16x32_f16((a),(b),(c),0,0,0)

#define L2E  1.44269504f
#define L2E2 2.88539008f

// Prepack fc0_w into per-timestep fp16 A-fragments (A[m=l][k=j], zeros elsewhere).
__global__ __launch_bounds__(64)
void pack_fc0(const float* __restrict__ fc0_w, float4t* __restrict__ dst)
{
    const int t = blockIdx.x, lane = threadIdx.x;
    const int m = lane & 15, q = lane >> 4;
    U16B v;
    #pragma unroll
    for (int i = 0; i < 8; ++i) {
        const int k = 8*q + i;
        float f = (m < L_ && k < H_) ? fc0_w[m*(T_*H_) + t*H_ + k] : 0.0f;
        v.h[i] = (_Float16)f;
    }
    dst[t*64 + lane] = v.f4;
}

// One wave per block; wave owns 16 batch elements. No barriers in the time loop
// (single-wave blocks; LDS round-trips are wave-internal, DS pipe is in-order).
__global__ __launch_bounds__(64)
void lstm_mfma(const float* __restrict__ x,
               const float* __restrict__ W_ih,
               const float* __restrict__ W_hh,
               const float* __restrict__ b_ih,
               const float* __restrict__ b_hh,
               const float* __restrict__ fc0_b,
               const float* __restrict__ out_w,
               const float* __restrict__ out_b,
               const float4t* __restrict__ fc0A,   // prepacked in d_ws
               float* __restrict__ out)
{
    // h staging: 16 elems x 40 halves (80B rows: 16B-aligned b128, no pow2 bank pathology)
    __shared__ __align__(16) _Float16 hL[16*40];
    __shared__ __align__(16) _Float16 actL[16*24];  // 48B rows

    const int lane = threadIdx.x;
    const int m = lane & 15;        // element col / A row-within-tile
    const int q = lane >> 4;        // quad
    const bool lo = (q < 2);
    const int elem = blockIdx.x * 16 + m;

    const float4t zf4 = {0.f, 0.f, 0.f, 0.f};

    // ---- gate A-fragments: Wcat[row][k]: k<24 -> W_hh, 24..28 -> W_ih, 29 -> bias, else 0
    half8 Ag[6];
    #pragma unroll
    for (int T6 = 0; T6 < 6; ++T6) {
        const int row = 16*T6 + m;
        float w[8];
        if (q < 3) {
            const float4t* pw = (const float4t*)(W_hh + row*H_ + 8*q);  // 32B aligned
            float4t wa = pw[0], wb = pw[1];
            #pragma unroll
            for (int i = 0; i < 4; ++i) { w[i] = wa[i]; w[4+i] = wb[i]; }
        } else {
            #pragma unroll
            for (int i = 0; i < 8; ++i) w[i] = 0.f;
            #pragma unroll
            for (int i = 0; i < I_; ++i) w[i] = W_ih[row*I_ + i];
            w[5] = b_ih[row] + b_hh[row];
        }
        U16B tw;
        #pragma unroll
        for (int i = 0; i < 8; ++i) tw.h[i] = (_Float16)w[i];
        Ag[T6] = tw.h8;
    }

    // ---- per-lane LDS addresses (halves) for h scatter/gather
    // fo-unit runs: q0:{8-11} q1:{12-15} q2:{0-3,16-19} q3:{4-7,20-23}
    const int u0  = lo ? (8 + 4*q) : (4*(q-2));
    const int hw0 = m*40 + u0;                 // first pair-run
    const int hw2 = m*40 + 16 + 4*(q-2);       // second run (q>=2 only)
    const int hr  = m*40 + q*8;                // b128 gather: h[8q..8q+7]

    // ---- x pointer (only q==3 lanes load x)
    const float* xp = x + (size_t)elem * (T_*I_);

    // ---- initial state: h=0, B-frag = [0 | x_0 | 1 | 0]
    U16B B;
    if (q < 3) B.f4 = zf4;
    else {
        B.h2[0] = pk2(xp[0], xp[1]);
        B.h2[1] = pk2(xp[2], xp[3]);
        B.h2[2] = pk2(xp[4], 1.0f);
        B.h2[3] = pk2(0.f, 0.f);
    }
    float c_[8];
    #pragma unroll
    for (int s = 0; s < 8; ++s) c_[s] = 0.f;
    float4t accF = zf4;

    // ================= time loop (no barriers) =================
    for (int t = 0; t < T_; ++t) {
        const float4t fa = fc0A[t*64 + lane];   // prefetched fc0 A-frag (fp16 packed)

        // 6 gate MFMAs: D[T] rows 16T+4q+r, col m
        float4t D0 = MFMA16(Ag[0], B.h8, zf4);
        float4t D1 = MFMA16(Ag[1], B.h8, zf4);
        float4t D2 = MFMA16(Ag[2], B.h8, zf4);
        float4t D3 = MFMA16(Ag[3], B.h8, zf4);
        float4t D4 = MFMA16(Ag[4], B.h8, zf4);
        float4t D5 = MFMA16(Ag[5], B.h8, zf4);

        float fs_[8], os_[8], p_[8];
        // slots 0-3: i=D0, g=D3, f = lo?D2:D1, o = lo?D5:D4
        #pragma unroll
        for (int r = 0; r < 4; ++r) {
            const float ir = D0[r];
            const float gr = D3[r];
            const float fr = lo ? D2[r] : D1[r];
            const float orr= lo ? D5[r] : D4[r];
            const float si = fast_rcp(1.f + fast_ex2(ir * -L2E));
            const float sg = fast_rcp(1.f + fast_ex2(gr * -L2E2));
            const float tg = 2.f*sg - 1.f;
            fs_[r] = fast_rcp(1.f + fast_ex2(fr * -L2E));
            os_[r] = fast_rcp(1.f + fast_ex2(orr * -L2E));
            p_[r]  = si * tg;
        }
        // slots 4-7: lo lanes -> (i from D1, g from D4); hi lanes -> (f from D2, o from D5)
        #pragma unroll
        for (int r = 0; r < 4; ++r) {
            const float u1 = lo ? D1[r] : D2[r];
            const float u2 = lo ? D4[r] : D5[r];
            const float a1 = fast_rcp(1.f + fast_ex2(u1 * -L2E));
            const float sc = lo ? -L2E2 : -L2E;
            const float s2 = fast_rcp(1.f + fast_ex2(u2 * sc));
            const float a2 = lo ? (2.f*s2 - 1.f) : s2;
            p_[4+r]  = a1 * a2;   // is*gt on lo (consumed by hi); junk on hi (never used)
            fs_[4+r] = a1;        // fs on hi
            os_[4+r] = a2;        // os on hi
        }
        // exchange p, update c/h on fo-lanes (slots 4-7 junk on lo: bounded, never stored)
        float hh[8];
        #pragma unroll
        for (int s = 0; s < 8; ++s) {
            const float pr = __shfl_xor(p_[s], 32, 64);
            c_[s] = fmaf(fs_[s], c_[s], pr);
            const float e  = fast_ex2(c_[s] * -L2E2);
            const float sg = fast_rcp(1.f + e);
            hh[s] = os_[s] * (2.f*sg - 1.f);
        }

        // scatter h (fp16) to canonical [elem][unit]
        *(half2t*)(&hL[hw0])     = pk2(hh[0], hh[1]);
        *(half2t*)(&hL[hw0 + 2]) = pk2(hh[2], hh[3]);
        if (!lo) {
            *(half2t*)(&hL[hw2])     = pk2(hh[4], hh[5]);
            *(half2t*)(&hL[hw2 + 2]) = pk2(hh[6], hh[7]);
        }
        __builtin_amdgcn_wave_barrier();   // order scatter before gather (single wave, in-order DS)

        // rebuild B-frag: q<3 gather h_t; q3 packs x_{t+1} (+bias one)
        if (q < 3) {
            B.f4 = *(const float4t*)(&hL[hr]);
        } else {
            const int tn = (t + 1 < T_) ? t + 1 : t;   // t=203: value unused (fc0 A is 0 for k>=24)
            B.h2[0] = pk2(xp[tn*5 + 0], xp[tn*5 + 1]);
            B.h2[1] = pk2(xp[tn*5 + 2], xp[tn*5 + 3]);
            B.h2[2] = pk2(xp[tn*5 + 4], 1.0f);
            B.h2[3] = pk2(0.f, 0.f);
        }

        // fc0 accumulation with h_t (rows k>=24 of B are zeroed in fc0A)
        U16B fA; fA.f4 = fa;
        accF = MFMA16(fA.h8, B.h8, accF);
    }

    // ================= epilogue =================
    // act[l][elem] = relu(fc0 + b): lane holds l = 4q+r
    float av[4];
    #pragma unroll
    for (int r = 0; r < 4; ++r) {
        const int l = 4*q + r;
        const float fb = (l < L_) ? fc0_b[l] : 0.f;
        const float v = accF[r] + fb;
        av[r] = (l < L_) ? fmaxf(v, 0.f) : 0.f;
    }
    *(half2t*)(&actL[m*24 + 4*q])     = pk2(av[0], av[1]);
    *(half2t*)(&actL[m*24 + 4*q + 2]) = pk2(av[2], av[3]);
    __builtin_amdgcn_wave_barrier();

    U16B Ba;
    if (q < 2) Ba.f4 = *(const float4t*)(&actL[m*24 + q*8]);
    else       Ba.f4 = zf4;            // k>=16 unused (out_w A-frag zero there)

    // out = act @ out_w^T + out_b : 39 MFMA tiles over 612 outputs
    for (int Tt = 0; Tt < 39; ++Tt) {
        const int row = 16*Tt + m;
        float w0=0.f,w1=0.f,w2=0.f,w3=0.f,w4=0.f,w5=0.f,w6=0.f,w7=0.f;
        if (row < O_ && q < 2) {
            const float2* p2 = (const float2*)(out_w + row*L_);   // 8B aligned
            if (q == 0) {
                float2 a = p2[0], b = p2[1], cc = p2[2], dd = p2[3];
                w0=a.x; w1=a.y; w2=b.x; w3=b.y; w4=cc.x; w5=cc.y; w6=dd.x; w7=dd.y;
            } else {
                float2 a = p2[4];
                w0=a.x; w1=a.y;
            }
        }
        U16B Aw;
        Aw.h2[0] = pk2(w0,w1); Aw.h2[1] = pk2(w2,w3);
        Aw.h2[2] = pk2(w4,w5); Aw.h2[3] = pk2(w6,w7);

        float4t dd = MFMA16(Aw.h8, Ba.h8, zf4);

        const int ob = 16*Tt + 4*q;
        if (ob < O_) {
            const float4t bias = *(const float4t*)(out_b + ob);   // 16B aligned
            #pragma unroll
            for (int r = 0; r < 4; ++r) dd[r] += bias[r];
            *(float4t*)(out + (size_t)elem*O_ + ob) = dd;
        }
    }
}

extern "C" void kernel_launch(void* const* d_in, const int* in_sizes, int n_in,
                              void* d_out, int out_size, void* d_ws, size_t ws_size,
                              hipStream_t stream)
{
    const float* x     = (const float*)d_in[0];
    const float* W_ih  = (const float*)d_in[1];
    const float* W_hh  = (const float*)d_in[2];
    const float* b_ih  = (const float*)d_in[3];
    const float* b_hh  = (const float*)d_in[4];
    const float* fc0_w = (const float*)d_in[5];
    const float* fc0_b = (const float*)d_in[6];
    const float* out_w = (const float*)d_in[7];
    const float* out_b = (const float*)d_in[8];
    float* out = (float*)d_out;
    (void)ws_size;

    pack_fc0<<<dim3(T_), dim3(64), 0, stream>>>(fc0_w, (float4t*)d_ws);
    lstm_mfma<<<dim3(Bsz/16), dim3(64), 0, stream>>>(
        x, W_ih, W_hh, b_ih, b_hh, fc0_b, out_w, out_b,
        (const float4t*)d_ws, out);
}

// Round 8
// 224.427 us; speedup vs baseline: 2.5443x; 1.4551x over previous
//
#include <hip/hip_runtime.h>
#include <math.h>

// Problem constants
#define T_  204
#define I_  5
#define H_  24
#define L_  10
#define O_  612
#define Bsz 8192

typedef _Float16 half8 __attribute__((ext_vector_type(8)));
typedef _Float16 half2t __attribute__((ext_vector_type(2)));
typedef float    float4t __attribute__((ext_vector_type(4)));

union U16B { float4t f4; half8 h8; float f[4]; _Float16 h[8]; half2t h2[4]; };

__device__ __forceinline__ float fast_rcp(float x){ return __builtin_amdgcn_rcpf(x); }
__device__ __forceinline__ float fast_ex2(float x){ return __builtin_amdgcn_exp2f(x); }
__device__ __forceinline__ half2t pk2(float a, float b){
    return __builtin_bit_cast(half2t, __builtin_amdgcn_cvt_pkrtz(a, b));
}

#define MFMA16(a,b,c) __builtin_amdgcn_mfma_f32_16x16x32_f16((a),(b),(c),0,0,0)

#define L2E  1.44269504f
#define L2E2 2.88539008f

__device__ __forceinline__ float sigm2(float x){            // sigmoid via exp2
    return fast_rcp(1.f + fast_ex2(x * -L2E));
}
__device__ __forceinline__ float tanh2(float x){            // tanh = 2*sigm(2x)-1
    return 2.f * fast_rcp(1.f + fast_ex2(x * -L2E2)) - 1.f;
}

// Prepack fc0_w into per-timestep fp16 A-fragments (A[m=l][k=j], zeros elsewhere).
__global__ __launch_bounds__(64)
void pack_fc0(const float* __restrict__ fc0_w, float4t* __restrict__ dst)
{
    const int t = blockIdx.x, lane = threadIdx.x;
    const int m = lane & 15, q = lane >> 4;
    U16B v;
    #pragma unroll
    for (int i = 0; i < 8; ++i) {
        const int k = 8*q + i;
        float f = (m < L_ && k < H_) ? fc0_w[m*(T_*H_) + t*H_ + k] : 0.0f;
        v.h[i] = (_Float16)f;
    }
    dst[t*64 + lane] = v.f4;
}

// One wave per block; wave owns 16 batch elements.
// R8: unit-ownership gate packing -- packed A row 16T+mm holds gate (mm&3) of
// unit 6*(mm>>2)+T, so lane (m,q)'s D regs r of tile T = gate r of unit 6q+T:
// the whole cell update is in-lane (R7's 8 ds_permute shuffles eliminated).
// Global loads (fc0A frag, next x) issued at iteration top (prefetch).
__global__ __launch_bounds__(64)
void lstm_mfma(const float* __restrict__ x,
               const float* __restrict__ W_ih,
               const float* __restrict__ W_hh,
               const float* __restrict__ b_ih,
               const float* __restrict__ b_hh,
               const float* __restrict__ fc0_b,
               const float* __restrict__ out_w,
               const float* __restrict__ out_b,
               const float4t* __restrict__ fc0A,   // prepacked in d_ws
               float* __restrict__ out)
{
    // h staging: 16 elems x 40 halves (80B rows; 2-way bank aliasing only)
    __shared__ __align__(16) _Float16 hL[16*40];
    __shared__ __align__(16) _Float16 actL[16*24];  // 48B rows

    const int lane = threadIdx.x;
    const int m = lane & 15;        // element col / A row-within-tile
    const int q = lane >> 4;        // quad
    const int elem = blockIdx.x * 16 + m;

    const float4t zf4 = {0.f, 0.f, 0.f, 0.f};

    // ---- gate A-fragments, unit-ownership permutation ----
    // lane (m,q) loads packed row mm=m of tile T: source gate g0=(m&3), unit 6*(m>>2)+T.
    // k<24 -> W_hh row, k=24..28 -> W_ih, k=29 -> bias, k=30,31 -> 0.
    half8 Ag[6];
    const int g0 = m & 3, ub = 6 * (m >> 2);
    #pragma unroll
    for (int T6 = 0; T6 < 6; ++T6) {
        const int srow = g0 * H_ + ub + T6;     // torch gate-major row
        float w[8];
        if (q < 3) {
            const float4t* pw = (const float4t*)(W_hh + srow*H_ + 8*q);  // 16B aligned
            float4t wa = pw[0], wb = pw[1];
            #pragma unroll
            for (int i = 0; i < 4; ++i) { w[i] = wa[i]; w[4+i] = wb[i]; }
        } else {
            #pragma unroll
            for (int i = 0; i < 8; ++i) w[i] = 0.f;
            #pragma unroll
            for (int i = 0; i < I_; ++i) w[i] = W_ih[srow*I_ + i];
            w[5] = b_ih[srow] + b_hh[srow];
        }
        U16B tw;
        #pragma unroll
        for (int i = 0; i < 8; ++i) tw.h[i] = (_Float16)w[i];
        Ag[T6] = tw.h8;
    }

    // ---- LDS addresses (halves): lane (m,q) owns h units 6q..6q+5 ----
    const int hwAddr = m*40 + 6*q;     // scatter: 3x half2
    const int hrAddr = m*40 + 8*q;     // gather: b128 (q<3), 16B aligned

    const float* xp = x + (size_t)elem * (T_*I_);

    // ---- initial B-frag: [h=0 | x_0 | 1 | 0,0] ----
    U16B B;
    if (q < 3) B.f4 = zf4;
    else {
        B.h2[0] = pk2(xp[0], xp[1]);
        B.h2[1] = pk2(xp[2], xp[3]);
        B.h2[2] = pk2(xp[4], 1.0f);
        B.h2[3] = pk2(0.f, 0.f);
    }
    float c_[6];
    #pragma unroll
    for (int s = 0; s < 6; ++s) c_[s] = 0.f;
    float4t accF = zf4;
    float4t fa = fc0A[lane];            // fc0 frag for t=0

    // ================= time loop =================
    for (int t = 0; t < T_; ++t) {
        // prefetch next-step operands (consumed at iteration bottom)
        const int tn = (t + 1 < T_) ? t + 1 : t;
        const float4t fan = fc0A[tn*64 + lane];
        float xn0=0.f, xn1=0.f, xn2=0.f, xn3=0.f, xn4=0.f;
        if (q == 3) {
            const float* xq = xp + tn*I_;
            xn0 = xq[0]; xn1 = xq[1]; xn2 = xq[2]; xn3 = xq[3]; xn4 = xq[4];
        }

        // 6 gate MFMAs
        float4t D0 = MFMA16(Ag[0], B.h8, zf4);
        float4t D1 = MFMA16(Ag[1], B.h8, zf4);
        float4t D2 = MFMA16(Ag[2], B.h8, zf4);
        float4t D3 = MFMA16(Ag[3], B.h8, zf4);
        float4t D4 = MFMA16(Ag[4], B.h8, zf4);
        float4t D5 = MFMA16(Ag[5], B.h8, zf4);

        // in-lane cell update: tile T -> (i,f,g,o) of unit 6q+T in regs 0..3
        float hh[6];
        {
            float4t D[6] = {D0, D1, D2, D3, D4, D5};
            #pragma unroll
            for (int T6 = 0; T6 < 6; ++T6) {
                const float si = sigm2(D[T6][0]);
                const float sf = sigm2(D[T6][1]);
                const float tg = tanh2(D[T6][2]);
                const float so = sigm2(D[T6][3]);
                c_[T6] = fmaf(sf, c_[T6], si * tg);
                hh[T6] = so * tanh2(c_[T6]);
            }
        }

        // scatter h (fp16) to canonical [elem][unit]
        *(half2t*)(&hL[hwAddr])     = pk2(hh[0], hh[1]);
        *(half2t*)(&hL[hwAddr + 2]) = pk2(hh[2], hh[3]);
        *(half2t*)(&hL[hwAddr + 4]) = pk2(hh[4], hh[5]);
        __builtin_amdgcn_wave_barrier();   // order scatter before gather (single wave, in-order DS)

        // rebuild B-frag: q<3 gather h_t; q3 packs x_{t+1} (+bias one)
        if (q < 3) {
            B.f4 = *(const float4t*)(&hL[hrAddr]);
        } else {
            B.h2[0] = pk2(xn0, xn1);
            B.h2[1] = pk2(xn2, xn3);
            B.h2[2] = pk2(xn4, 1.0f);
            B.h2[3] = pk2(0.f, 0.f);
        }

        // fc0 accumulation with h_t (rows k>=24 of fc0A are zero)
        U16B fA; fA.f4 = fa;
        accF = MFMA16(fA.h8, B.h8, accF);
        fa = fan;
    }

    // ================= epilogue (validated in R7) =================
    float av[4];
    #pragma unroll
    for (int r = 0; r < 4; ++r) {
        const int l = 4*q + r;
        const float fb = (l < L_) ? fc0_b[l] : 0.f;
        const float v = accF[r] + fb;
        av[r] = (l < L_) ? fmaxf(v, 0.f) : 0.f;
    }
    *(half2t*)(&actL[m*24 + 4*q])     = pk2(av[0], av[1]);
    *(half2t*)(&actL[m*24 + 4*q + 2]) = pk2(av[2], av[3]);
    __builtin_amdgcn_wave_barrier();

    U16B Ba;
    if (q < 2) Ba.f4 = *(const float4t*)(&actL[m*24 + q*8]);
    else       Ba.f4 = zf4;            // k>=16 unused (out_w A-frag zero there)

    // out = act @ out_w^T + out_b : 39 MFMA tiles over 612 outputs
    for (int Tt = 0; Tt < 39; ++Tt) {
        const int row = 16*Tt + m;
        float w0=0.f,w1=0.f,w2=0.f,w3=0.f,w4=0.f,w5=0.f,w6=0.f,w7=0.f;
        if (row < O_ && q < 2) {
            const float2* p2 = (const float2*)(out_w + row*L_);   // 8B aligned
            if (q == 0) {
                float2 a = p2[0], b = p2[1], cc = p2[2], dd = p2[3];
                w0=a.x; w1=a.y; w2=b.x; w3=b.y; w4=cc.x; w5=cc.y; w6=dd.x; w7=dd.y;
            } else {
                float2 a = p2[4];
                w0=a.x; w1=a.y;
            }
        }
        U16B Aw;
        Aw.h2[0] = pk2(w0,w1); Aw.h2[1] = pk2(w2,w3);
        Aw.h2[2] = pk2(w4,w5); Aw.h2[3] = pk2(w6,w7);

        float4t dd = MFMA16(Aw.h8, Ba.h8, zf4);

        const int ob = 16*Tt + 4*q;
        if (ob < O_) {
            const float4t bias = *(const float4t*)(out_b + ob);   // 16B aligned
            #pragma unroll
            for (int r = 0; r < 4; ++r) dd[r] += bias[r];
            *(float4t*)(out + (size_t)elem*O_ + ob) = dd;
        }
    }
}

extern "C" void kernel_launch(void* const* d_in, const int* in_sizes, int n_in,
                              void* d_out, int out_size, void* d_ws, size_t ws_size,
                              hipStream_t stream)
{
    const float* x     = (const float*)d_in[0];
    const float* W_ih  = (const float*)d_in[1];
    const float* W_hh  = (const float*)d_in[2];
    const float* b_ih  = (const float*)d_in[3];
    const float* b_hh  = (const float*)d_in[4];
    const float* fc0_w = (const float*)d_in[5];
    const float* fc0_b = (const float*)d_in[6];
    const float* out_w = (const float*)d_in[7];
    const float* out_b = (const float*)d_in[8];
    float* out = (float*)d_out;
    (void)ws_size;

    pack_fc0<<<dim3(T_), dim3(64), 0, stream>>>(fc0_w, (float4t*)d_ws);
    lstm_mfma<<<dim3(Bsz/16), dim3(64), 0, stream>>>(
        x, W_ih, W_hh, b_ih, b_hh, fc0_b, out_w, out_b,
        (const float4t*)d_ws, out);
}